// Round 13
// baseline (33347.839 us; speedup 1.0000x reference)
//
#include <hip/hip_runtime.h>
#include <stdint.h>
#include <stddef.h>

#define HH 256
#define WW 256
#define NCH 20
#define KH 128
#define TSX 16
#define TSY 16
#define NTHR 512

// JAX threefry2x32 (20 rounds), exact.
__host__ __device__ inline void tf2x32(uint32_t k0, uint32_t k1,
                                       uint32_t x0, uint32_t x1,
                                       uint32_t* o0, uint32_t* o1) {
  uint32_t ks0 = k0, ks1 = k1, ks2 = k0 ^ k1 ^ 0x1BD11BDAu;
  x0 += ks0; x1 += ks1;
#define RND(r) { x0 += x1; x1 = (x1 << (r)) | (x1 >> (32 - (r))); x1 ^= x0; }
  RND(13) RND(15) RND(26) RND(6)   x0 += ks1; x1 += ks2 + 1u;
  RND(17) RND(29) RND(16) RND(24)  x0 += ks2; x1 += ks0 + 2u;
  RND(13) RND(15) RND(26) RND(6)   x0 += ks0; x1 += ks1 + 3u;
  RND(17) RND(29) RND(16) RND(24)  x0 += ks1; x1 += ks2 + 4u;
  RND(13) RND(15) RND(26) RND(6)   x0 += ks2; x1 += ks0 + 5u;
#undef RND
  *o0 = x0; *o1 = x1;
}

__device__ inline float fire_of(uint32_t fk0, uint32_t fk1, uint32_t f) {
  // JAX partitionable threefry: counts hi=0, lo=f; bits = o0 ^ o1
  uint32_t o0, o1;
  tf2x32(fk0, fk1, 0u, f, &o0, &o1);
  uint32_t bits = o0 ^ o1;
  float u = __uint_as_float((bits >> 9) | 0x3f800000u) - 1.0f;
  return (u < 0.5f) ? 1.0f : 0.0f;
}

// One NCA step, TWO threads per pixel (even lane: ch 0..9, odd lane: ch 10..19).
// r6/r10/r12 lesson: ~95-float live set either spills (VGPR<=64/128 split) or caps
// occupancy at 2 waves/SIMD. Splitting the channel dim halves the live set to ~62
// -> fits 64 arch VGPRs (the split the allocator picks at waves_per_eu(4,4)),
// zero churn, 4 waves/SIMD. h completed via one __shfl_xor (commutative add:
// bit-exact both lanes). W1/W2/b1 all in LDS as broadcast reads.
__global__ __attribute__((amdgpu_flat_work_group_size(NTHR, NTHR), amdgpu_waves_per_eu(4, 4)))
void nca_step(
    const float* __restrict__ xin, float* __restrict__ xout,
    const float* __restrict__ W1, const float* __restrict__ b1,
    const float* __restrict__ W2, uint32_t fk0, uint32_t fk1)
{
  __shared__ float xs[NCH][18][18];   // 25.92 KB halo tile (16x16 px + 1 halo)
  __shared__ float w1s[KH * 64];      // 32.77 KB: [k][0..29]=half-A (ctr0..9,sob0..9), [k][32..61]=half-B
  __shared__ float w2b[KH * 24];      // 12.29 KB: [k][0..9]=W2 ch0..9, [k][12..21]=ch10..19, [k][22]=b1

  const int tid = threadIdx.x;
  const int bx = blockIdx.x, by = blockIdx.y, bb = blockIdx.z;
  const int x0t = bx * TSX, y0t = by * TSY;
  const float* xb = xin + (size_t)bb * (NCH * HH * WW);

  // ---- stage W1 into LDS, permuted so each half's 30 weights are contiguous ----
  // global col c -> local: c<10 -> c | 10..19 -> c+22 | 20..39 -> c-10 | 40..59 -> c+2
  for (int i = tid; i < KH * 60; i += NTHR) {
    int kk = i / 60, c = i - kk * 60;
    int dc = (c < 10) ? c : (c < 20) ? c + 22 : (c < 40) ? c - 10 : c + 2;
    w1s[kk * 64 + dc] = W1[i];
  }
  // ---- stage W2^T + b1 (c-major for coalesced global reads) ----
  for (int i = tid; i < 24 * KH; i += NTHR) {
    int c = i >> 7, kk = i & 127;
    float v = 0.f;
    if (c < 10) v = W2[c * KH + kk];
    else if (c >= 12 && c < 22) v = W2[(c - 2) * KH + kk];
    else if (c == 22) v = b1[kk];
    w2b[kk * 24 + c] = v;
  }
  // ---- stage halo tile (reflect padding) ----
  for (int idx = tid; idx < NCH * 18 * 18; idx += NTHR) {
    int c  = idx / 324;
    int r  = idx - c * 324;
    int ly = r / 18;
    int lx = r - ly * 18;
    int gy = y0t + ly - 1;
    int gx = x0t + lx - 1;
    gy = (gy < 0) ? -gy : gy;  gy = (gy >= HH) ? (2 * HH - 2 - gy) : gy;
    gx = (gx < 0) ? -gx : gx;  gx = (gx >= WW) ? (2 * WW - 2 - gx) : gx;
    xs[c][ly][lx] = xb[c * (HH * WW) + gy * WW + gx];
  }
  __syncthreads();

  const int half = tid & 1;           // 0: channels 0..9, 1: channels 10..19
  const int pix  = tid >> 1;          // 0..255 within tile
  const int tx = pix & 15, ty = pix >> 4;
  const int cb = half * 10;

  // ---- perceive for this thread's 10 channels: p[j]=center, p[10+2j]=sx, p[11+2j]=sy ----
  float p[30];
#pragma unroll
  for (int j = 0; j < 10; ++j) {
    int c = cb + j;
    float a00 = xs[c][ty    ][tx], a01 = xs[c][ty    ][tx + 1], a02 = xs[c][ty    ][tx + 2];
    float a10 = xs[c][ty + 1][tx], a11 = xs[c][ty + 1][tx + 1], a12 = xs[c][ty + 1][tx + 2];
    float a20 = xs[c][ty + 2][tx], a21 = xs[c][ty + 2][tx + 1], a22 = xs[c][ty + 2][tx + 2];
    p[j] = a11;
    p[10 + 2 * j] = ((a02 - a00) + 2.f * (a12 - a10) + (a22 - a20)) * 0.125f;
    p[11 + 2 * j] = ((a20 - a00) + 2.f * (a21 - a01) + (a22 - a02)) * 0.125f;
  }

  float dxv[10];
#pragma unroll
  for (int j = 0; j < 10; ++j) dxv[j] = 0.f;

  // ---- fused MLP: each lane does a 30-term partial of h[k]; shfl completes it ----
#pragma unroll 1
  for (int k = 0; k < KH; ++k) {
    const float* wrow = &w1s[k * 64 + half * 32];   // 16B-aligned (half*128B)
    const float bk = w2b[k * 24 + 22];              // broadcast (1 addr)
    float a0 = half ? 0.f : bk;                     // bias seeded once (even lane)
    float a1 = 0.f, a2 = 0.f, a3 = 0.f;
#pragma unroll
    for (int q = 0; q < 7; ++q) {
      float4 w = *(const float4*)&wrow[4 * q];      // 2-addr broadcast ds_read_b128
      a0 = fmaf(w.x, p[4 * q    ], a0);
      a1 = fmaf(w.y, p[4 * q + 1], a1);
      a2 = fmaf(w.z, p[4 * q + 2], a2);
      a3 = fmaf(w.w, p[4 * q + 3], a3);
    }
    float2 wt = *(const float2*)&wrow[28];
    a0 = fmaf(wt.x, p[28], a0);
    a1 = fmaf(wt.y, p[29], a1);
    float ps = (a0 + a1) + (a2 + a3);
    float h = fmaxf(ps + __shfl_xor(ps, 1), 0.f);   // partner's partial (DPP)

    const float* w2r = &w2b[k * 24 + half * 12];    // 16B-aligned (half*48B)
    float4 u0 = *(const float4*)&w2r[0];
    float4 u1 = *(const float4*)&w2r[4];
    float2 u2 = *(const float2*)&w2r[8];
    dxv[0] = fmaf(u0.x, h, dxv[0]);
    dxv[1] = fmaf(u0.y, h, dxv[1]);
    dxv[2] = fmaf(u0.z, h, dxv[2]);
    dxv[3] = fmaf(u0.w, h, dxv[3]);
    dxv[4] = fmaf(u1.x, h, dxv[4]);
    dxv[5] = fmaf(u1.y, h, dxv[5]);
    dxv[6] = fmaf(u1.z, h, dxv[6]);
    dxv[7] = fmaf(u1.w, h, dxv[7]);
    dxv[8] = fmaf(u2.x, h, dxv[8]);
    dxv[9] = fmaf(u2.y, h, dxv[9]);
  }

  // ---- stochastic fire mask (exact JAX partitionable threefry) ----
  const int gy = y0t + ty, gx = x0t + tx;
  float fire = fire_of(fk0, fk1, ((uint32_t)bb << 16) | ((uint32_t)gy << 8) | (uint32_t)gx);

  size_t base = (size_t)bb * (NCH * HH * WW) + (size_t)gy * WW + gx;
#pragma unroll
  for (int j = 0; j < 10; ++j) {
    float add = dxv[j] * fire;
    if (j < 3) add = half ? add : 0.f;   // global ch 0..2 (even lane, j<3) immutable
    xout[base + (size_t)(cb + j) * (HH * WW)] = p[j] + add;
  }
}

extern "C" void kernel_launch(void* const* d_in, const int* in_sizes, int n_in,
                              void* d_out, int out_size, void* d_ws, size_t ws_size,
                              hipStream_t stream) {
  const float* x  = (const float*)d_in[0];
  const float* W1 = (const float*)d_in[1];
  const float* b1 = (const float*)d_in[2];
  const float* W2 = (const float*)d_in[3];
  const int steps = 64;   // fixed by setup_inputs()

  float* bufWs  = (float*)d_ws;   // ping buffer, 41.94 MB
  float* bufOut = (float*)d_out;

  dim3 grid(WW / TSX, HH / TSY, 8);
  dim3 block(NTHR);

  const float* src = x;
  for (int s = 0; s < steps; ++s) {
    uint32_t fk0, fk1;
    tf2x32(0u, 42u, 0u, (uint32_t)s, &fk0, &fk1);   // fold_in(key(42), s)
    float* dst = ((steps - 1 - s) & 1) ? bufWs : bufOut;  // final step -> d_out
    nca_step<<<grid, block, 0, stream>>>(src, dst, W1, b1, W2, fk0, fk1);
    src = dst;
  }
}